// Round 1
// baseline (11463.979 us; speedup 1.0000x reference)
//
#include <hip/hip_runtime.h>
#include <math.h>

#define L_  4
#define B_  2
#define Q_  1024
#define M_  1024
#define D_  1024
#define H_  16
#define DH_ 64
#define DI_ 4096
#define KL_ (M_ + Q_)   // 2048

// ---------------- positional embedding p[KL][D] ----------------
__global__ __launch_bounds__(256) void pos_emb_kernel(float* __restrict__ p) {
    int idx = blockIdx.x * 256 + threadIdx.x;           // < KL_*D_
    int k = idx >> 10;                                   // / D_
    int i = idx & (D_ - 1);
    float pos = (float)(KL_ - 1 - k);
    int j = (i < D_ / 2) ? i : (i - D_ / 2);
    float invf = powf(10000.0f, -((float)(2 * j) / (float)D_));
    float ang = pos * invf;
    p[idx] = (i < D_ / 2) ? sinf(ang) : cosf(ang);
}

// ---------------- concat memory[l] and x into xmem [B][KL][D] ----------------
__global__ __launch_bounds__(256) void concat_kernel(float* __restrict__ xmem,
                                                     const float* __restrict__ mem_l,
                                                     const float* __restrict__ xc) {
    int idx = blockIdx.x * 256 + threadIdx.x;           // < B_*KL_*D_
    int d = idx & (D_ - 1);
    int k = (idx >> 10) & (KL_ - 1);
    int b = idx >> 21;
    xmem[idx] = (k < M_) ? mem_l[((size_t)(b * M_ + k)) * D_ + d]
                         : xc[((size_t)(b * Q_ + (k - M_))) * D_ + d];
}

// ---------------- fp32 GEMM C[M,N] = A[M,K] @ B[K,N] (+bias)(+relu) ----------------
// MODE: 0 = plain, 1 = +bias, 2 = +bias +relu
template <int MODE>
__global__ __launch_bounds__(256) void gemm_k(const float* __restrict__ A,
                                              const float* __restrict__ B,
                                              const float* __restrict__ bias,
                                              float* __restrict__ C,
                                              int M, int N, int K) {
    __shared__ float As[16][65];   // transposed A tile: As[k][m]
    __shared__ float Bs[16][64];
    int tid = threadIdx.x;
    int tx = tid & 15, ty = tid >> 4;
    int row0 = blockIdx.y * 64;
    int col0 = blockIdx.x * 64;
    int ar = tid >> 2, ac4 = tid & 3;    // A tile load: 64 rows x 4 float4
    int br = tid >> 4, bc4 = tid & 15;   // B tile load: 16 rows x 16 float4
    float acc[4][4] = {};
    for (int k0 = 0; k0 < K; k0 += 16) {
        float4 av = *(const float4*)(A + (size_t)(row0 + ar) * K + k0 + ac4 * 4);
        As[ac4 * 4 + 0][ar] = av.x;
        As[ac4 * 4 + 1][ar] = av.y;
        As[ac4 * 4 + 2][ar] = av.z;
        As[ac4 * 4 + 3][ar] = av.w;
        *(float4*)(&Bs[br][bc4 * 4]) =
            *(const float4*)(B + (size_t)(k0 + br) * N + col0 + bc4 * 4);
        __syncthreads();
#pragma unroll
        for (int kt = 0; kt < 16; kt++) {
            float a0 = As[kt][ty * 4 + 0];
            float a1 = As[kt][ty * 4 + 1];
            float a2 = As[kt][ty * 4 + 2];
            float a3 = As[kt][ty * 4 + 3];
            float b0 = Bs[kt][tx * 4 + 0];
            float b1 = Bs[kt][tx * 4 + 1];
            float b2 = Bs[kt][tx * 4 + 2];
            float b3 = Bs[kt][tx * 4 + 3];
            acc[0][0] += a0 * b0; acc[0][1] += a0 * b1; acc[0][2] += a0 * b2; acc[0][3] += a0 * b3;
            acc[1][0] += a1 * b0; acc[1][1] += a1 * b1; acc[1][2] += a1 * b2; acc[1][3] += a1 * b3;
            acc[2][0] += a2 * b0; acc[2][1] += a2 * b1; acc[2][2] += a2 * b2; acc[2][3] += a2 * b3;
            acc[3][0] += a3 * b0; acc[3][1] += a3 * b1; acc[3][2] += a3 * b2; acc[3][3] += a3 * b3;
        }
        __syncthreads();
    }
#pragma unroll
    for (int i = 0; i < 4; i++) {
#pragma unroll
        for (int j = 0; j < 4; j++) {
            float v = acc[i][j];
            int col = col0 + tx * 4 + j;
            if (MODE >= 1) v += bias[col];
            if (MODE == 2) v = fmaxf(v, 0.0f);
            C[(size_t)(row0 + ty * 4 + i) * N + col] = v;
        }
    }
}

// ---------------- fused attention ----------------
// One block = (b, h, 4 consecutive q rows). 4 waves; wave w owns q = qbase + w.
// score[q,k] = scale * ((qh[q]+rw).kh[k] + (qh[q]+rr).r[k + Q-1 - q]), masked k > q+M.
__global__ __launch_bounds__(256) void attn_kernel(const float* __restrict__ heads,
                                                   const float* __restrict__ rbuf,
                                                   const float* __restrict__ rwb,
                                                   const float* __restrict__ rrb,
                                                   float* __restrict__ attno) {
    __shared__ float qw[4][DH_], qr[4][DH_];
    __shared__ float kh_s[64][DH_ + 1];
    __shared__ float vh_s[64][DH_ + 1];
    __shared__ float r_s[68][DH_ + 1];

    int tid = threadIdx.x;
    int w = tid >> 6, lane = tid & 63;
    int blk = blockIdx.x;
    int qbase = (blk & (Q_ / 4 - 1)) * 4;
    int bh = blk >> 8;                 // Q_/4 = 256 blocks per (b,h)
    int h = bh & (H_ - 1);
    int b = bh >> 4;
    int q = qbase + w;

    float qhv = heads[((size_t)(b * KL_ + M_ + q)) * 3072 + h * DH_ + lane];
    qw[w][lane] = qhv + rwb[h * DH_ + lane];
    qr[w][lane] = qhv + rrb[h * DH_ + lane];

    float m = -1e30f, lsum = 0.0f, acc = 0.0f;
    const float scale = 0.125f;        // 1/sqrt(64)
    int qmax = qbase + 3;
    int ntiles = (qmax + M_) / 64 + 1;

    for (int t = 0; t < ntiles; t++) {
        int k0 = t * 64;
        __syncthreads();
        // stage kh, vh tiles (coalesced row loads, 4 waves strided)
        for (int r = w; r < 64; r += 4) {
            size_t base = ((size_t)(b * KL_ + k0 + r)) * 3072 + h * DH_ + lane;
            kh_s[r][lane] = heads[base + 1024];
            vh_s[r][lane] = heads[base + 2048];
        }
        // stage r rows i0 .. i0+67 (clamped; clamped rows are masked anyway)
        int i0 = k0 + (Q_ - 1) - qmax;
        for (int r = w; r < 68; r += 4) {
            int ii = i0 + r;
            ii = ii < 0 ? 0 : (ii > KL_ - 1 ? KL_ - 1 : ii);
            r_s[r][lane] = rbuf[(size_t)ii * (H_ * DH_) + h * DH_ + lane];
        }
        __syncthreads();

        // scores: lane j handles k = k0 + j
        int k = k0 + lane;
        int rrow = lane + 3 - w;       // (k + Q-1 - q) - i0
        float s = 0.0f;
#pragma unroll 16
        for (int d = 0; d < DH_; d++) {
            s += qw[w][d] * kh_s[lane][d] + qr[w][d] * r_s[rrow][d];
        }
        s *= scale;
        bool valid = (k <= q + M_);
        if (!valid) s = -1e30f;

        float tmax = s;
        for (int off = 32; off; off >>= 1) tmax = fmaxf(tmax, __shfl_xor(tmax, off));
        float mnew = fmaxf(m, tmax);
        float c = expf(m - mnew);
        float pv = valid ? expf(s - mnew) : 0.0f;
        float psum = pv;
        for (int off = 32; off; off >>= 1) psum += __shfl_xor(psum, off);
        lsum = lsum * c + psum;
        acc *= c;
        m = mnew;

        // PV: acc_d += sum_kk p[kk] * vh[kk][d]   (p broadcast via shfl)
#pragma unroll 16
        for (int kk = 0; kk < 64; kk++) {
            float pkk = __shfl(pv, kk);
            acc += pkk * vh_s[kk][lane];
        }
    }
    attno[((size_t)(b * Q_ + q)) * (H_ * DH_) + h * DH_ + lane] = acc / lsum;
}

// ---------------- layernorm: x = LN(x + add) * g + b ----------------
__global__ __launch_bounds__(256) void ln_kernel(float* __restrict__ x,
                                                 const float* __restrict__ add,
                                                 const float* __restrict__ g,
                                                 const float* __restrict__ bb) {
    __shared__ float red[256];
    int row = blockIdx.x;
    int tid = threadIdx.x;
    float v[4];
    float s = 0.0f;
#pragma unroll
    for (int i = 0; i < 4; i++) {
        int c = tid + i * 256;
        v[i] = x[(size_t)row * D_ + c] + add[(size_t)row * D_ + c];
        s += v[i];
    }
    red[tid] = s;
    __syncthreads();
    for (int o = 128; o; o >>= 1) {
        if (tid < o) red[tid] += red[tid + o];
        __syncthreads();
    }
    float mu = red[0] / D_;
    __syncthreads();
    float sq = 0.0f;
#pragma unroll
    for (int i = 0; i < 4; i++) {
        float dd = v[i] - mu;
        sq += dd * dd;
    }
    red[tid] = sq;
    __syncthreads();
    for (int o = 128; o; o >>= 1) {
        if (tid < o) red[tid] += red[tid + o];
        __syncthreads();
    }
    float var = red[0] / D_;
    float rs = rsqrtf(var + 1e-5f);
#pragma unroll
    for (int i = 0; i < 4; i++) {
        int c = tid + i * 256;
        x[(size_t)row * D_ + c] = (v[i] - mu) * rs * g[c] + bb[c];
    }
}

extern "C" void kernel_launch(void* const* d_in, const int* in_sizes, int n_in,
                              void* d_out, int out_size, void* d_ws, size_t ws_size,
                              hipStream_t stream) {
    const float* x    = (const float*)d_in[0];
    const float* mem  = (const float*)d_in[1];
    const float* Wqkv = (const float*)d_in[2];
    const float* Wr   = (const float*)d_in[3];
    const float* Wo   = (const float*)d_in[4];
    const float* rwb  = (const float*)d_in[5];
    const float* rrb  = (const float*)d_in[6];
    const float* ln1g = (const float*)d_in[7];
    const float* ln1b = (const float*)d_in[8];
    const float* ln2g = (const float*)d_in[9];
    const float* ln2b = (const float*)d_in[10];
    const float* Wff1 = (const float*)d_in[11];
    const float* bff1 = (const float*)d_in[12];
    const float* Wff2 = (const float*)d_in[13];
    const float* bff2 = (const float*)d_in[14];

    float* xc = (float*)d_out;                       // evolving x, [B,Q,D]
    float* ws = (float*)d_ws;

    // workspace layout (floats)
    float* rb    = ws;                               // [KL, H*DH]       2M
    float* xmem  = rb + (size_t)KL_ * D_;            // [B, KL, D]       4M
    float* heads = xmem + (size_t)B_ * KL_ * D_;     // [B, KL, 3072]    12.58M
    float* attno = heads + (size_t)B_ * KL_ * 3 * H_ * DH_;  // [B,Q,H*DH] 2M
    float* addbuf= attno + (size_t)B_ * Q_ * H_ * DH_;       // [B,Q,D]    2M (attn-proj out / ff2 out)
    float* ff1o  = addbuf + (size_t)B_ * Q_ * D_;    // [B, Q, DI]       8M
    float* p     = ff1o;                             // p aliases ff1o slot (used only up front)

    // p and r = p @ W_r (shared across layers)
    pos_emb_kernel<<<(KL_ * D_) / 256, 256, 0, stream>>>(p);
    gemm_k<0><<<dim3((H_ * DH_) / 64, KL_ / 64), 256, 0, stream>>>(
        p, Wr, nullptr, rb, KL_, H_ * DH_, D_);

    // x -> xc
    hipMemcpyAsync(xc, x, (size_t)B_ * Q_ * D_ * sizeof(float),
                   hipMemcpyDeviceToDevice, stream);

    for (int l = 0; l < L_; l++) {
        const float* mem_l = mem + (size_t)l * B_ * M_ * D_;
        concat_kernel<<<(B_ * KL_ * D_) / 256, 256, 0, stream>>>(xmem, mem_l, xc);

        gemm_k<0><<<dim3(3072 / 64, (B_ * KL_) / 64), 256, 0, stream>>>(
            xmem, Wqkv + (size_t)l * D_ * 3072, nullptr, heads, B_ * KL_, 3072, D_);

        attn_kernel<<<B_ * H_ * (Q_ / 4), 256, 0, stream>>>(heads, rb, rwb, rrb, attno);

        gemm_k<0><<<dim3(D_ / 64, (B_ * Q_) / 64), 256, 0, stream>>>(
            attno, Wo + (size_t)l * H_ * DH_ * D_, nullptr, addbuf, B_ * Q_, D_, H_ * DH_);

        ln_kernel<<<B_ * Q_, 256, 0, stream>>>(xc, addbuf, ln1g + l * D_, ln1b + l * D_);

        gemm_k<2><<<dim3(DI_ / 64, (B_ * Q_) / 64), 256, 0, stream>>>(
            xc, Wff1 + (size_t)l * D_ * DI_, bff1 + (size_t)l * DI_, ff1o, B_ * Q_, DI_, D_);

        gemm_k<1><<<dim3(D_ / 64, (B_ * Q_) / 64), 256, 0, stream>>>(
            ff1o, Wff2 + (size_t)l * DI_ * D_, bff2 + (size_t)l * D_, addbuf, B_ * Q_, D_, DI_);

        ln_kernel<<<B_ * Q_, 256, 0, stream>>>(xc, addbuf, ln2g + l * D_, ln2b + l * D_);
    }
}

// Round 2
// 4632.272 us; speedup vs baseline: 2.4748x; 2.4748x over previous
//
#include <hip/hip_runtime.h>
#include <math.h>

#define L_  4
#define B_  2
#define Q_  1024
#define M_  1024
#define D_  1024
#define H_  16
#define DH_ 64
#define DI_ 4096
#define KL_ (M_ + Q_)   // 2048

typedef __attribute__((ext_vector_type(8))) short short8v;  // 8 bf16 (4 VGPRs)
typedef __attribute__((ext_vector_type(4))) float f32x4;

__device__ __forceinline__ short f2bf(float f) {
    union { float f; unsigned u; } x; x.f = f;
    return (short)((x.u + 0x7FFFu + ((x.u >> 16) & 1)) >> 16);  // RNE
}
__device__ __forceinline__ unsigned pack2bf(float a, float b) {
    return (unsigned)(unsigned short)f2bf(a) | ((unsigned)(unsigned short)f2bf(b) << 16);
}

// ---------------- positional embedding p[KL][D] ----------------
__global__ __launch_bounds__(256) void pos_emb_kernel(float* __restrict__ p) {
    int idx = blockIdx.x * 256 + threadIdx.x;
    int k = idx >> 10;
    int i = idx & (D_ - 1);
    float pos = (float)(KL_ - 1 - k);
    int j = (i < D_ / 2) ? i : (i - D_ / 2);
    float invf = powf(10000.0f, -((float)(2 * j) / (float)D_));
    float ang = pos * invf;
    p[idx] = (i < D_ / 2) ? sinf(ang) : cosf(ang);
}

// ---------------- concat memory[l] and x into xmem [B][KL][D] ----------------
__global__ __launch_bounds__(256) void concat_kernel(float* __restrict__ xmem,
                                                     const float* __restrict__ mem_l,
                                                     const float* __restrict__ xc) {
    int idx = blockIdx.x * 256 + threadIdx.x;
    int d = idx & (D_ - 1);
    int k = (idx >> 10) & (KL_ - 1);
    int b = idx >> 21;
    xmem[idx] = (k < M_) ? mem_l[((size_t)(b * M_ + k)) * D_ + d]
                         : xc[((size_t)(b * Q_ + (k - M_))) * D_ + d];
}

// ---------------- heads K/V parts -> bf16 compact [B*KL][1024] ----------------
__global__ __launch_bounds__(256) void kvconv_kernel(const float* __restrict__ heads,
                                                     short* __restrict__ kbf,
                                                     short* __restrict__ vbf) {
    int i = (blockIdx.x * 256 + threadIdx.x) * 4;   // over B_*KL_*1024
    int row = i >> 10, c = i & 1023;
    float4 kv = *(const float4*)(heads + (size_t)row * 3072 + 1024 + c);
    float4 vv = *(const float4*)(heads + (size_t)row * 3072 + 2048 + c);
    uint2 ko, vo;
    ko.x = pack2bf(kv.x, kv.y); ko.y = pack2bf(kv.z, kv.w);
    vo.x = pack2bf(vv.x, vv.y); vo.y = pack2bf(vv.z, vv.w);
    *(uint2*)(kbf + i) = ko;
    *(uint2*)(vbf + i) = vo;
}

// ---------------- generic f32 -> bf16 ----------------
__global__ __launch_bounds__(256) void bfconv_kernel(const float* __restrict__ in,
                                                     short* __restrict__ out) {
    int i = (blockIdx.x * 256 + threadIdx.x) * 4;
    float4 v = *(const float4*)(in + i);
    uint2 o; o.x = pack2bf(v.x, v.y); o.y = pack2bf(v.z, v.w);
    *(uint2*)(out + i) = o;
}

// ---------------- fp32 GEMM C[M,N] = A[M,K] @ B[K,N] (+bias)(+relu) ----------------
template <int MODE>
__global__ __launch_bounds__(256) void gemm_k(const float* __restrict__ A,
                                              const float* __restrict__ B,
                                              const float* __restrict__ bias,
                                              float* __restrict__ C,
                                              int M, int N, int K) {
    __shared__ float As[16][65];
    __shared__ float Bs[16][64];
    int tid = threadIdx.x;
    int tx = tid & 15, ty = tid >> 4;
    int row0 = blockIdx.y * 64;
    int col0 = blockIdx.x * 64;
    int ar = tid >> 2, ac4 = tid & 3;
    int br = tid >> 4, bc4 = tid & 15;
    float acc[4][4] = {};
    for (int k0 = 0; k0 < K; k0 += 16) {
        float4 av = *(const float4*)(A + (size_t)(row0 + ar) * K + k0 + ac4 * 4);
        As[ac4 * 4 + 0][ar] = av.x;
        As[ac4 * 4 + 1][ar] = av.y;
        As[ac4 * 4 + 2][ar] = av.z;
        As[ac4 * 4 + 3][ar] = av.w;
        *(float4*)(&Bs[br][bc4 * 4]) =
            *(const float4*)(B + (size_t)(k0 + br) * N + col0 + bc4 * 4);
        __syncthreads();
#pragma unroll
        for (int kt = 0; kt < 16; kt++) {
            float a0 = As[kt][ty * 4 + 0];
            float a1 = As[kt][ty * 4 + 1];
            float a2 = As[kt][ty * 4 + 2];
            float a3 = As[kt][ty * 4 + 3];
            float b0 = Bs[kt][tx * 4 + 0];
            float b1 = Bs[kt][tx * 4 + 1];
            float b2 = Bs[kt][tx * 4 + 2];
            float b3 = Bs[kt][tx * 4 + 3];
            acc[0][0] += a0 * b0; acc[0][1] += a0 * b1; acc[0][2] += a0 * b2; acc[0][3] += a0 * b3;
            acc[1][0] += a1 * b0; acc[1][1] += a1 * b1; acc[1][2] += a1 * b2; acc[1][3] += a1 * b3;
            acc[2][0] += a2 * b0; acc[2][1] += a2 * b1; acc[2][2] += a2 * b2; acc[2][3] += a2 * b3;
            acc[3][0] += a3 * b0; acc[3][1] += a3 * b1; acc[3][2] += a3 * b2; acc[3][3] += a3 * b3;
        }
        __syncthreads();
    }
#pragma unroll
    for (int i = 0; i < 4; i++) {
#pragma unroll
        for (int j = 0; j < 4; j++) {
            float v = acc[i][j];
            int col = col0 + tx * 4 + j;
            if (MODE >= 1) v += bias[col];
            if (MODE == 2) v = fmaxf(v, 0.0f);
            C[(size_t)(row0 + ty * 4 + i) * N + col] = v;
        }
    }
}

// ---------------- MFMA fused attention ----------------
// block = (b, h, 64 q-rows); 4 waves, wave w owns rows [q0+16w, q0+16w+16).
// Per 64-key tile: AC = Qw·K^T (MFMA), BDraw = Qr·R^T over a per-wave 80-wide
// j-window (MFMA -> LDS -> q-dependent shift read), online softmax in D-frag
// layout, PV via LDS round-trip of P into A-operand layout.
__global__ __launch_bounds__(256, 2) void attn_mfma(const float* __restrict__ heads,
                                                    const short* __restrict__ kbf,
                                                    const short* __restrict__ vbf,
                                                    const short* __restrict__ rbh,
                                                    const float* __restrict__ rwb,
                                                    const float* __restrict__ rrb,
                                                    float* __restrict__ attno) {
    __shared__ short K_s[64][72];
    __shared__ short V_T[64][72];      // transposed: V_T[d][key]
    __shared__ short R_s[128][72];
    __shared__ union {
        short q[2][64][72];            // Qw, Qr staging (block start only)
        struct { float bd[4][16][84]; short p[4][16][72]; } s;  // per-wave scratch
    } un;

    const int tid = threadIdx.x;
    const int lane = tid & 63, w = tid >> 6;
    const int l15 = lane & 15, l4 = lane >> 4;

    int blk = blockIdx.x;
    int qp = blk & 15;
    int bh = blk >> 4;
    int h = bh & 15, b = bh >> 4;
    // pair short and long q-tiles so co-resident pairs have equal total work
    int qi = (qp & 1) ? (15 - (qp >> 1)) : (qp >> 1);
    int q0 = qi * 64;
    int ntiles = qi + 17;

    // ---- stage Qw/Qr (bf16, biases fused) ----
    for (int uq = tid; uq < 1024; uq += 256) {
        int row = uq >> 4, d0 = (uq & 15) * 4;
        float4 qv = *(const float4*)(heads + ((size_t)(b * KL_ + M_ + q0 + row)) * 3072 + h * 64 + d0);
        float4 bw = *(const float4*)(rwb + h * 64 + d0);
        float4 br = *(const float4*)(rrb + h * 64 + d0);
        un.q[0][row][d0 + 0] = f2bf(qv.x + bw.x);
        un.q[0][row][d0 + 1] = f2bf(qv.y + bw.y);
        un.q[0][row][d0 + 2] = f2bf(qv.z + bw.z);
        un.q[0][row][d0 + 3] = f2bf(qv.w + bw.w);
        un.q[1][row][d0 + 0] = f2bf(qv.x + br.x);
        un.q[1][row][d0 + 1] = f2bf(qv.y + br.y);
        un.q[1][row][d0 + 2] = f2bf(qv.z + br.z);
        un.q[1][row][d0 + 3] = f2bf(qv.w + br.w);
    }
    __syncthreads();
    short8v qwf0 = *(const short8v*)&un.q[0][16 * w + l15][8 * l4];
    short8v qwf1 = *(const short8v*)&un.q[0][16 * w + l15][32 + 8 * l4];
    short8v qrf0 = *(const short8v*)&un.q[1][16 * w + l15][8 * l4];
    short8v qrf1 = *(const short8v*)&un.q[1][16 * w + l15][32 + 8 * l4];

    f32x4 o[4];
    float m_r[4], l_r[4];
#pragma unroll
    for (int j = 0; j < 4; j++) o[j] = (f32x4){0.f, 0.f, 0.f, 0.f};
#pragma unroll
    for (int r = 0; r < 4; r++) { m_r[r] = -1e30f; l_r[r] = 0.0f; }

    for (int t = 0; t < ntiles; t++) {
        int k0 = t * 64;
        __syncthreads();   // protect LDS reuse (also seals Q_s reads vs bd writes at t=0)
        // stage K and V^T (bf16, 8 elems/unit)
        for (int uu = tid; uu < 512; uu += 256) {
            int row = uu >> 3, d0 = (uu & 7) << 3;
            size_t gbase = ((size_t)(b * KL_ + k0 + row)) * 1024 + h * 64 + d0;
            *(uint4*)&K_s[row][d0] = *(const uint4*)(kbf + gbase);
            union { uint4 v; short s[8]; } cv;
            cv.v = *(const uint4*)(vbf + gbase);
#pragma unroll
            for (int i = 0; i < 8; i++) V_T[d0 + i][row] = cv.s[i];
        }
        // stage R window: rows j0 .. j0+127 (clamped rows feed only masked elems)
        int j0 = k0 + (Q_ - 1) - q0 - 63;
        for (int uu = tid; uu < 1024; uu += 256) {
            int rr = uu >> 3, d0 = (uu & 7) << 3;
            int jj = j0 + rr;
            jj = jj < 0 ? 0 : (jj > KL_ - 1 ? KL_ - 1 : jj);
            *(uint4*)&R_s[rr][d0] = *(const uint4*)(rbh + (size_t)jj * 1024 + h * 64 + d0);
        }
        __syncthreads();

        // ---- AC = Qw · K^T ----
        f32x4 ac[4];
#pragma unroll
        for (int j = 0; j < 4; j++) {
            f32x4 z = {0.f, 0.f, 0.f, 0.f};
            short8v b0 = *(const short8v*)&K_s[16 * j + l15][8 * l4];
            short8v b1 = *(const short8v*)&K_s[16 * j + l15][32 + 8 * l4];
            z = __builtin_amdgcn_mfma_f32_16x16x32_bf16(qwf0, b0, z, 0, 0, 0);
            z = __builtin_amdgcn_mfma_f32_16x16x32_bf16(qwf1, b1, z, 0, 0, 0);
            ac[j] = z;
        }
        // ---- BDraw = Qr · R^T over per-wave 80-wide window -> LDS ----
        int rbase = 16 * (3 - w);
#pragma unroll
        for (int jb = 0; jb < 5; jb++) {
            f32x4 z = {0.f, 0.f, 0.f, 0.f};
            short8v b0 = *(const short8v*)&R_s[rbase + 16 * jb + l15][8 * l4];
            short8v b1 = *(const short8v*)&R_s[rbase + 16 * jb + l15][32 + 8 * l4];
            z = __builtin_amdgcn_mfma_f32_16x16x32_bf16(qrf0, b0, z, 0, 0, 0);
            z = __builtin_amdgcn_mfma_f32_16x16x32_bf16(qrf1, b1, z, 0, 0, 0);
#pragma unroll
            for (int r = 0; r < 4; r++)
                un.s.bd[w][4 * l4 + r][16 * jb + l15] = z[r];
        }

        // ---- s = (AC + shifted BD) * scale, mask, online softmax ----
        float sv[4][4], mloc[4];
#pragma unroll
        for (int r = 0; r < 4; r++) mloc[r] = -1e30f;
#pragma unroll
        for (int j = 0; j < 4; j++) {
#pragma unroll
            for (int r = 0; r < 4; r++) {
                int row = 4 * l4 + r;
                int kl = 16 * j + l15;
                float bdv = un.s.bd[w][row][kl + 15 - row];
                float s = (ac[j][r] + bdv) * 0.125f;
                if (k0 + kl > q0 + 16 * w + row + M_) s = -1e30f;
                sv[j][r] = s;
                mloc[r] = fmaxf(mloc[r], s);
            }
        }
#pragma unroll
        for (int r = 0; r < 4; r++) {
            float v = mloc[r];
            v = fmaxf(v, __shfl_xor(v, 1));
            v = fmaxf(v, __shfl_xor(v, 2));
            v = fmaxf(v, __shfl_xor(v, 4));
            v = fmaxf(v, __shfl_xor(v, 8));
            float mnew = fmaxf(m_r[r], v);
            float c = __expf(m_r[r] - mnew);
            m_r[r] = mnew;
            l_r[r] *= c;
#pragma unroll
            for (int jd = 0; jd < 4; jd++) o[jd][r] *= c;
            mloc[r] = 0.0f;   // reuse as psum
        }
#pragma unroll
        for (int j = 0; j < 4; j++) {
#pragma unroll
            for (int r = 0; r < 4; r++) {
                float pp = __expf(sv[j][r] - m_r[r]);
                sv[j][r] = pp;
                mloc[r] += pp;
            }
        }
#pragma unroll
        for (int r = 0; r < 4; r++) {
            float v = mloc[r];
            v += __shfl_xor(v, 1);
            v += __shfl_xor(v, 2);
            v += __shfl_xor(v, 4);
            v += __shfl_xor(v, 8);
            l_r[r] += v;
        }

        // ---- P -> LDS (bf16) -> A-frags; PV MFMA ----
#pragma unroll
        for (int j = 0; j < 4; j++) {
#pragma unroll
            for (int r = 0; r < 4; r++)
                un.s.p[w][4 * l4 + r][16 * j + l15] = f2bf(sv[j][r]);
        }
        short8v pa0 = *(const short8v*)&un.s.p[w][l15][8 * l4];
        short8v pa1 = *(const short8v*)&un.s.p[w][l15][32 + 8 * l4];
#pragma unroll
        for (int jd = 0; jd < 4; jd++) {
            short8v v0 = *(const short8v*)&V_T[16 * jd + l15][8 * l4];
            short8v v1 = *(const short8v*)&V_T[16 * jd + l15][32 + 8 * l4];
            o[jd] = __builtin_amdgcn_mfma_f32_16x16x32_bf16(pa0, v0, o[jd], 0, 0, 0);
            o[jd] = __builtin_amdgcn_mfma_f32_16x16x32_bf16(pa1, v1, o[jd], 0, 0, 0);
        }
    }

    // ---- normalize + store ----
#pragma unroll
    for (int jd = 0; jd < 4; jd++) {
#pragma unroll
        for (int r = 0; r < 4; r++) {
            int qg = q0 + 16 * w + 4 * l4 + r;
            int dv = 16 * jd + l15;
            attno[((size_t)(b * Q_ + qg)) * (H_ * DH_) + h * 64 + dv] = o[jd][r] / l_r[r];
        }
    }
}

// ---------------- layernorm: x = LN(x + add) * g + b ----------------
__global__ __launch_bounds__(256) void ln_kernel(float* __restrict__ x,
                                                 const float* __restrict__ add,
                                                 const float* __restrict__ g,
                                                 const float* __restrict__ bb) {
    __shared__ float red[256];
    int row = blockIdx.x;
    int tid = threadIdx.x;
    float v[4];
    float s = 0.0f;
#pragma unroll
    for (int i = 0; i < 4; i++) {
        int c = tid + i * 256;
        v[i] = x[(size_t)row * D_ + c] + add[(size_t)row * D_ + c];
        s += v[i];
    }
    red[tid] = s;
    __syncthreads();
    for (int o = 128; o; o >>= 1) {
        if (tid < o) red[tid] += red[tid + o];
        __syncthreads();
    }
    float mu = red[0] / D_;
    __syncthreads();
    float sq = 0.0f;
#pragma unroll
    for (int i = 0; i < 4; i++) {
        float dd = v[i] - mu;
        sq += dd * dd;
    }
    red[tid] = sq;
    __syncthreads();
    for (int o = 128; o; o >>= 1) {
        if (tid < o) red[tid] += red[tid + o];
        __syncthreads();
    }
    float var = red[0] / D_;
    float rs = rsqrtf(var + 1e-5f);
#pragma unroll
    for (int i = 0; i < 4; i++) {
        int c = tid + i * 256;
        x[(size_t)row * D_ + c] = (v[i] - mu) * rs * g[c] + bb[c];
    }
}

extern "C" void kernel_launch(void* const* d_in, const int* in_sizes, int n_in,
                              void* d_out, int out_size, void* d_ws, size_t ws_size,
                              hipStream_t stream) {
    const float* x    = (const float*)d_in[0];
    const float* mem  = (const float*)d_in[1];
    const float* Wqkv = (const float*)d_in[2];
    const float* Wr   = (const float*)d_in[3];
    const float* Wo   = (const float*)d_in[4];
    const float* rwb  = (const float*)d_in[5];
    const float* rrb  = (const float*)d_in[6];
    const float* ln1g = (const float*)d_in[7];
    const float* ln1b = (const float*)d_in[8];
    const float* ln2g = (const float*)d_in[9];
    const float* ln2b = (const float*)d_in[10];
    const float* Wff1 = (const float*)d_in[11];
    const float* bff1 = (const float*)d_in[12];
    const float* Wff2 = (const float*)d_in[13];
    const float* bff2 = (const float*)d_in[14];

    float* xc = (float*)d_out;
    float* ws = (float*)d_ws;

    // workspace layout (floats)
    float* rb    = ws;                                        // [KL,1024]  8MB
    float* xmem  = rb + (size_t)KL_ * D_;                     // [B,KL,D]   16MB
    float* heads = xmem + (size_t)B_ * KL_ * D_;              // [B,KL,3072] 50.3MB
    float* attno = heads + (size_t)B_ * KL_ * 3 * H_ * DH_;   // [B,Q,1024] 8MB
    float* addbuf= attno + (size_t)B_ * Q_ * H_ * DH_;        // [B,Q,D]    8MB
    float* ff1o  = addbuf + (size_t)B_ * Q_ * D_;             // [B,Q,DI]   32MB
    float* p     = ff1o;                                      // transient alias
    // bf16 buffers alias ff1o (dead outside FF phase):
    short* rbh = (short*)ff1o;                                // [KL,1024] bf16, 4MB
    short* kbf = (short*)(ff1o + 1048576);                    // [B*KL,1024] bf16, 8.4MB
    short* vbf = (short*)(ff1o + 1048576 + 2097152);          // [B*KL,1024] bf16, 8.4MB

    pos_emb_kernel<<<(KL_ * D_) / 256, 256, 0, stream>>>(p);
    gemm_k<0><<<dim3((H_ * DH_) / 64, KL_ / 64), 256, 0, stream>>>(
        p, Wr, nullptr, rb, KL_, H_ * DH_, D_);

    hipMemcpyAsync(xc, x, (size_t)B_ * Q_ * D_ * sizeof(float),
                   hipMemcpyDeviceToDevice, stream);

    for (int l = 0; l < L_; l++) {
        const float* mem_l = mem + (size_t)l * B_ * M_ * D_;

        bfconv_kernel<<<(KL_ * D_) / 1024, 256, 0, stream>>>(rb, rbh);
        concat_kernel<<<(B_ * KL_ * D_) / 256, 256, 0, stream>>>(xmem, mem_l, xc);

        gemm_k<0><<<dim3(3072 / 64, (B_ * KL_) / 64), 256, 0, stream>>>(
            xmem, Wqkv + (size_t)l * D_ * 3072, nullptr, heads, B_ * KL_, 3072, D_);

        kvconv_kernel<<<(B_ * KL_ * 1024) / 1024, 256, 0, stream>>>(heads, kbf, vbf);

        attn_mfma<<<B_ * H_ * (Q_ / 64), 256, 0, stream>>>(
            heads, kbf, vbf, rbh, rwb, rrb, attno);

        gemm_k<0><<<dim3(D_ / 64, (B_ * Q_) / 64), 256, 0, stream>>>(
            attno, Wo + (size_t)l * H_ * DH_ * D_, nullptr, addbuf, B_ * Q_, D_, H_ * DH_);

        ln_kernel<<<B_ * Q_, 256, 0, stream>>>(xc, addbuf, ln1g + l * D_, ln1b + l * D_);

        gemm_k<2><<<dim3(DI_ / 64, (B_ * Q_) / 64), 256, 0, stream>>>(
            xc, Wff1 + (size_t)l * D_ * DI_, bff1 + (size_t)l * DI_, ff1o, B_ * Q_, DI_, D_);

        gemm_k<1><<<dim3(D_ / 64, (B_ * Q_) / 64), 256, 0, stream>>>(
            ff1o, Wff2 + (size_t)l * DI_ * D_, bff2 + (size_t)l * D_, addbuf, B_ * Q_, D_, DI_);

        ln_kernel<<<B_ * Q_, 256, 0, stream>>>(xc, addbuf, ln2g + l * D_, ln2b + l * D_);
    }
}

// Round 3
// 1396.196 us; speedup vs baseline: 8.2109x; 3.3178x over previous
//
#include <hip/hip_runtime.h>
#include <math.h>

#define L_  4
#define B_  2
#define Q_  1024
#define M_  1024
#define D_  1024
#define H_  16
#define DH_ 64
#define DI_ 4096
#define KL_ (M_ + Q_)   // 2048

typedef __attribute__((ext_vector_type(8))) short short8v;  // 8 bf16 (4 VGPRs)
typedef __attribute__((ext_vector_type(4))) float f32x4;

__device__ __forceinline__ short f2bf(float f) {
    union { float f; unsigned u; } x; x.f = f;
    return (short)((x.u + 0x7FFFu + ((x.u >> 16) & 1)) >> 16);  // RNE
}
__device__ __forceinline__ unsigned pack2bf(float a, float b) {
    return (unsigned)(unsigned short)f2bf(a) | ((unsigned)(unsigned short)f2bf(b) << 16);
}
__device__ __forceinline__ float bf2f(unsigned short u) {
    union { unsigned u; float f; } x; x.u = (unsigned)u << 16; return x.f;
}
__device__ __forceinline__ void gload_lds16(const short* g, short* l) {
    __builtin_amdgcn_global_load_lds((const __attribute__((address_space(1))) unsigned int*)(const void*)g,
                                     (__attribute__((address_space(3))) unsigned int*)(void*)l, 16, 0, 0);
}

// ---------------- positional embedding p[KL][D] (bf16) ----------------
__global__ __launch_bounds__(256) void pos_emb_bf(short* __restrict__ p) {
    int idx = blockIdx.x * 256 + threadIdx.x;
    int k = idx >> 10;
    int i = idx & (D_ - 1);
    float pos = (float)(KL_ - 1 - k);
    int j = (i < D_ / 2) ? i : (i - D_ / 2);
    float invf = powf(10000.0f, -((float)(2 * j) / (float)D_));
    float ang = pos * invf;
    p[idx] = f2bf((i < D_ / 2) ? sinf(ang) : cosf(ang));
}

// ---------------- concat memory[l] and x into xmemb [B][KL][D] bf16 ----------------
__global__ __launch_bounds__(256) void concat_bf(short* __restrict__ xmemb,
                                                 const float* __restrict__ mem_l,
                                                 const float* __restrict__ xc) {
    int idx = blockIdx.x * 256 + threadIdx.x;
    int d = idx & (D_ - 1);
    int k = (idx >> 10) & (KL_ - 1);
    int b = idx >> 21;
    float v = (k < M_) ? mem_l[((size_t)(b * M_ + k)) * D_ + d]
                       : xc[((size_t)(b * Q_ + (k - M_))) * D_ + d];
    xmemb[idx] = f2bf(v);
}

// ---------------- tiled transpose + f32->bf16: in[K][N] -> out[N][K] ----------------
__global__ __launch_bounds__(256) void transp_bf(const float* __restrict__ in,
                                                 short* __restrict__ out,
                                                 int K, int N) {
    __shared__ float t[32][33];
    int r = threadIdx.x >> 3, c4 = (threadIdx.x & 7) * 4;
    float4 v = *(const float4*)(in + (size_t)(blockIdx.y * 32 + r) * N + blockIdx.x * 32 + c4);
    t[r][c4 + 0] = v.x; t[r][c4 + 1] = v.y; t[r][c4 + 2] = v.z; t[r][c4 + 3] = v.w;
    __syncthreads();
    uint2 o;
    o.x = pack2bf(t[c4 + 0][r], t[c4 + 1][r]);
    o.y = pack2bf(t[c4 + 2][r], t[c4 + 3][r]);
    *(uint2*)(out + (size_t)(blockIdx.x * 32 + r) * K + blockIdx.y * 32 + c4) = o;
}

// ---------------- bf16 MFMA GEMM: C[M,N] = A[M,K] @ BT[N,K]^T ----------------
// 128x128 tile, BK=32, 4 waves (each a 64x64 quadrant, 4x4 16x16 frags).
// OMODE: 0 = f32 out (Cf), 1 = bf16 out (C0), 2 = qkv 3-way bf16 split (C0/C1/C2)
template <int BIAS, int RELU, int OMODE>
__global__ __launch_bounds__(256, 2) void gemm_bf(const short* __restrict__ A,
                                                  const short* __restrict__ BT,
                                                  const float* __restrict__ bias,
                                                  float* __restrict__ Cf,
                                                  short* __restrict__ C0,
                                                  short* __restrict__ C1,
                                                  short* __restrict__ C2,
                                                  int M, int N, int K) {
    __shared__ short A_s[128][32];
    __shared__ short B_s[128][32];
    const int tid = threadIdx.x;
    const int lane = tid & 63, w = tid >> 6;
    const int l15 = lane & 15, l4 = lane >> 4;
    const int wr = w >> 1, wc = w & 1;
    const int row0 = blockIdx.y * 128, col0 = blockIdx.x * 128;

    const int lrow = lane >> 2;           // 0..15
    const int lk = (lane & 3) * 8;        // element offset within K-window
    const short* Ag = A + (size_t)(row0 + 32 * w) * K;
    const short* Bg = BT + (size_t)(col0 + 32 * w) * K;

    f32x4 acc[4][4] = {};

    for (int k0 = 0; k0 < K; k0 += 32) {
        __syncthreads();
        gload_lds16(Ag + (size_t)lrow * K + k0 + lk,        &A_s[32 * w][0]);
        gload_lds16(Ag + (size_t)(16 + lrow) * K + k0 + lk, &A_s[32 * w + 16][0]);
        gload_lds16(Bg + (size_t)lrow * K + k0 + lk,        &B_s[32 * w][0]);
        gload_lds16(Bg + (size_t)(16 + lrow) * K + k0 + lk, &B_s[32 * w + 16][0]);
        __syncthreads();
        short8v a[4], bfr[4];
#pragma unroll
        for (int m = 0; m < 4; m++) a[m] = *(const short8v*)&A_s[64 * wr + 16 * m + l15][8 * l4];
#pragma unroll
        for (int n = 0; n < 4; n++) bfr[n] = *(const short8v*)&B_s[64 * wc + 16 * n + l15][8 * l4];
#pragma unroll
        for (int m = 0; m < 4; m++)
#pragma unroll
            for (int n = 0; n < 4; n++)
                acc[m][n] = __builtin_amdgcn_mfma_f32_16x16x32_bf16(a[m], bfr[n], acc[m][n], 0, 0, 0);
    }

#pragma unroll
    for (int n = 0; n < 4; n++) {
        int col = col0 + 64 * wc + 16 * n + l15;
        float bv = BIAS ? bias[col] : 0.0f;
#pragma unroll
        for (int m = 0; m < 4; m++) {
#pragma unroll
            for (int r = 0; r < 4; r++) {
                int row = row0 + 64 * wr + 16 * m + 4 * l4 + r;
                float v = acc[m][n][r] + bv;
                if (RELU) v = fmaxf(v, 0.0f);
                if (OMODE == 0) {
                    Cf[(size_t)row * N + col] = v;
                } else if (OMODE == 1) {
                    C0[(size_t)row * N + col] = f2bf(v);
                } else {
                    int part = col >> 10, cc = col & 1023;
                    short* dst = part == 0 ? C0 : (part == 1 ? C1 : C2);
                    dst[(size_t)row * 1024 + cc] = f2bf(v);
                }
            }
        }
    }
}

// ---------------- MFMA fused attention ----------------
__global__ __launch_bounds__(256, 2) void attn_mfma(const short* __restrict__ qbf,
                                                    const short* __restrict__ kbf,
                                                    const short* __restrict__ vbf,
                                                    const short* __restrict__ rbh,
                                                    const float* __restrict__ rwb,
                                                    const float* __restrict__ rrb,
                                                    short* __restrict__ attnob) {
    __shared__ short K_s[64][72];
    __shared__ short V_T[64][72];      // transposed: V_T[d][key]
    __shared__ short R_s[128][72];
    __shared__ union {
        short q[2][64][72];            // Qw, Qr staging (block start only)
        struct { float bd[4][16][84]; short p[4][16][72]; } s;
    } un;

    const int tid = threadIdx.x;
    const int lane = tid & 63, w = tid >> 6;
    const int l15 = lane & 15, l4 = lane >> 4;

    int blk = blockIdx.x;
    int qp = blk & 15;
    int bh = blk >> 4;
    int h = bh & 15, b = bh >> 4;
    int qi = (qp & 1) ? (15 - (qp >> 1)) : (qp >> 1);
    int q0 = qi * 64;
    int ntiles = qi + 17;

    // ---- stage Qw/Qr (bf16, biases fused) ----
    for (int uq = tid; uq < 512; uq += 256) {
        int row = uq >> 3, d0 = (uq & 7) * 8;
        union { uint4 u; unsigned short us[8]; } qv;
        qv.u = *(const uint4*)(qbf + ((size_t)(b * KL_ + M_ + q0 + row)) * 1024 + h * 64 + d0);
        float4 bw0 = *(const float4*)(rwb + h * 64 + d0);
        float4 bw1 = *(const float4*)(rwb + h * 64 + d0 + 4);
        float4 br0 = *(const float4*)(rrb + h * 64 + d0);
        float4 br1 = *(const float4*)(rrb + h * 64 + d0 + 4);
        float bwv[8] = {bw0.x, bw0.y, bw0.z, bw0.w, bw1.x, bw1.y, bw1.z, bw1.w};
        float brv[8] = {br0.x, br0.y, br0.z, br0.w, br1.x, br1.y, br1.z, br1.w};
#pragma unroll
        for (int i = 0; i < 8; i++) {
            float qf = bf2f(qv.us[i]);
            un.q[0][row][d0 + i] = f2bf(qf + bwv[i]);
            un.q[1][row][d0 + i] = f2bf(qf + brv[i]);
        }
    }
    __syncthreads();
    short8v qwf0 = *(const short8v*)&un.q[0][16 * w + l15][8 * l4];
    short8v qwf1 = *(const short8v*)&un.q[0][16 * w + l15][32 + 8 * l4];
    short8v qrf0 = *(const short8v*)&un.q[1][16 * w + l15][8 * l4];
    short8v qrf1 = *(const short8v*)&un.q[1][16 * w + l15][32 + 8 * l4];

    f32x4 o[4];
    float m_r[4], l_r[4];
#pragma unroll
    for (int j = 0; j < 4; j++) o[j] = (f32x4){0.f, 0.f, 0.f, 0.f};
#pragma unroll
    for (int r = 0; r < 4; r++) { m_r[r] = -1e30f; l_r[r] = 0.0f; }

    for (int t = 0; t < ntiles; t++) {
        int k0 = t * 64;
        __syncthreads();
        for (int uu = tid; uu < 512; uu += 256) {
            int row = uu >> 3, d0 = (uu & 7) << 3;
            size_t gbase = ((size_t)(b * KL_ + k0 + row)) * 1024 + h * 64 + d0;
            *(uint4*)&K_s[row][d0] = *(const uint4*)(kbf + gbase);
            union { uint4 v; short s[8]; } cv;
            cv.v = *(const uint4*)(vbf + gbase);
#pragma unroll
            for (int i = 0; i < 8; i++) V_T[d0 + i][row] = cv.s[i];
        }
        int j0 = k0 + (Q_ - 1) - q0 - 63;
        for (int uu = tid; uu < 1024; uu += 256) {
            int rr = uu >> 3, d0 = (uu & 7) << 3;
            int jj = j0 + rr;
            jj = jj < 0 ? 0 : (jj > KL_ - 1 ? KL_ - 1 : jj);
            *(uint4*)&R_s[rr][d0] = *(const uint4*)(rbh + (size_t)jj * 1024 + h * 64 + d0);
        }
        __syncthreads();

        // ---- AC = Qw · K^T ----
        f32x4 ac[4];
#pragma unroll
        for (int j = 0; j < 4; j++) {
            f32x4 z = {0.f, 0.f, 0.f, 0.f};
            short8v b0 = *(const short8v*)&K_s[16 * j + l15][8 * l4];
            short8v b1 = *(const short8v*)&K_s[16 * j + l15][32 + 8 * l4];
            z = __builtin_amdgcn_mfma_f32_16x16x32_bf16(qwf0, b0, z, 0, 0, 0);
            z = __builtin_amdgcn_mfma_f32_16x16x32_bf16(qwf1, b1, z, 0, 0, 0);
            ac[j] = z;
        }
        // ---- BDraw over per-wave 80-wide window -> LDS ----
        int rbase = 16 * (3 - w);
#pragma unroll
        for (int jb = 0; jb < 5; jb++) {
            f32x4 z = {0.f, 0.f, 0.f, 0.f};
            short8v b0 = *(const short8v*)&R_s[rbase + 16 * jb + l15][8 * l4];
            short8v b1 = *(const short8v*)&R_s[rbase + 16 * jb + l15][32 + 8 * l4];
            z = __builtin_amdgcn_mfma_f32_16x16x32_bf16(qrf0, b0, z, 0, 0, 0);
            z = __builtin_amdgcn_mfma_f32_16x16x32_bf16(qrf1, b1, z, 0, 0, 0);
#pragma unroll
            for (int r = 0; r < 4; r++)
                un.s.bd[w][4 * l4 + r][16 * jb + l15] = z[r];
        }

        // ---- s = (AC + shifted BD) * scale, mask, online softmax ----
        float sv[4][4], mloc[4];
#pragma unroll
        for (int r = 0; r < 4; r++) mloc[r] = -1e30f;
#pragma unroll
        for (int j = 0; j < 4; j++) {
#pragma unroll
            for (int r = 0; r < 4; r++) {
                int row = 4 * l4 + r;
                int kl = 16 * j + l15;
                float bdv = un.s.bd[w][row][kl + 15 - row];
                float s = (ac[j][r] + bdv) * 0.125f;
                if (k0 + kl > q0 + 16 * w + row + M_) s = -1e30f;
                sv[j][r] = s;
                mloc[r] = fmaxf(mloc[r], s);
            }
        }
#pragma unroll
        for (int r = 0; r < 4; r++) {
            float v = mloc[r];
            v = fmaxf(v, __shfl_xor(v, 1));
            v = fmaxf(v, __shfl_xor(v, 2));
            v = fmaxf(v, __shfl_xor(v, 4));
            v = fmaxf(v, __shfl_xor(v, 8));
            float mnew = fmaxf(m_r[r], v);
            float c = __expf(m_r[r] - mnew);
            m_r[r] = mnew;
            l_r[r] *= c;
#pragma unroll
            for (int jd = 0; jd < 4; jd++) o[jd][r] *= c;
            mloc[r] = 0.0f;
        }
#pragma unroll
        for (int j = 0; j < 4; j++) {
#pragma unroll
            for (int r = 0; r < 4; r++) {
                float pp = __expf(sv[j][r] - m_r[r]);
                sv[j][r] = pp;
                mloc[r] += pp;
            }
        }
#pragma unroll
        for (int r = 0; r < 4; r++) {
            float v = mloc[r];
            v += __shfl_xor(v, 1);
            v += __shfl_xor(v, 2);
            v += __shfl_xor(v, 4);
            v += __shfl_xor(v, 8);
            l_r[r] += v;
        }

        // ---- P -> LDS (bf16) -> A-frags; PV MFMA ----
#pragma unroll
        for (int j = 0; j < 4; j++) {
#pragma unroll
            for (int r = 0; r < 4; r++)
                un.s.p[w][4 * l4 + r][16 * j + l15] = f2bf(sv[j][r]);
        }
        short8v pa0 = *(const short8v*)&un.s.p[w][l15][8 * l4];
        short8v pa1 = *(const short8v*)&un.s.p[w][l15][32 + 8 * l4];
#pragma unroll
        for (int jd = 0; jd < 4; jd++) {
            short8v v0 = *(const short8v*)&V_T[16 * jd + l15][8 * l4];
            short8v v1 = *(const short8v*)&V_T[16 * jd + l15][32 + 8 * l4];
            o[jd] = __builtin_amdgcn_mfma_f32_16x16x32_bf16(pa0, v0, o[jd], 0, 0, 0);
            o[jd] = __builtin_amdgcn_mfma_f32_16x16x32_bf16(pa1, v1, o[jd], 0, 0, 0);
        }
    }

#pragma unroll
    for (int jd = 0; jd < 4; jd++) {
#pragma unroll
        for (int r = 0; r < 4; r++) {
            int qg = q0 + 16 * w + 4 * l4 + r;
            int dv = 16 * jd + l15;
            attnob[((size_t)(b * Q_ + qg)) * (H_ * DH_) + h * 64 + dv] = f2bf(o[jd][r] / l_r[r]);
        }
    }
}

// ---------------- layernorm: x = LN(x + add) * g + b ; dual f32+bf16 out ----------------
__global__ __launch_bounds__(256) void ln_kernel(float* __restrict__ x,
                                                 short* __restrict__ xb,
                                                 const float* __restrict__ add,
                                                 const float* __restrict__ g,
                                                 const float* __restrict__ bb) {
    __shared__ float red[256];
    int row = blockIdx.x;
    int tid = threadIdx.x;
    float v[4];
    float s = 0.0f;
#pragma unroll
    for (int i = 0; i < 4; i++) {
        int c = tid + i * 256;
        v[i] = x[(size_t)row * D_ + c] + add[(size_t)row * D_ + c];
        s += v[i];
    }
    red[tid] = s;
    __syncthreads();
    for (int o = 128; o; o >>= 1) {
        if (tid < o) red[tid] += red[tid + o];
        __syncthreads();
    }
    float mu = red[0] / D_;
    __syncthreads();
    float sq = 0.0f;
#pragma unroll
    for (int i = 0; i < 4; i++) {
        float dd = v[i] - mu;
        sq += dd * dd;
    }
    red[tid] = sq;
    __syncthreads();
    for (int o = 128; o; o >>= 1) {
        if (tid < o) red[tid] += red[tid + o];
        __syncthreads();
    }
    float var = red[0] / D_;
    float rs = rsqrtf(var + 1e-5f);
#pragma unroll
    for (int i = 0; i < 4; i++) {
        int c = tid + i * 256;
        float ov = (v[i] - mu) * rs * g[c] + bb[c];
        x[(size_t)row * D_ + c] = ov;
        xb[(size_t)row * D_ + c] = f2bf(ov);
    }
}

extern "C" void kernel_launch(void* const* d_in, const int* in_sizes, int n_in,
                              void* d_out, int out_size, void* d_ws, size_t ws_size,
                              hipStream_t stream) {
    const float* x    = (const float*)d_in[0];
    const float* mem  = (const float*)d_in[1];
    const float* Wqkv = (const float*)d_in[2];
    const float* Wr   = (const float*)d_in[3];
    const float* Wo   = (const float*)d_in[4];
    const float* rwb  = (const float*)d_in[5];
    const float* rrb  = (const float*)d_in[6];
    const float* ln1g = (const float*)d_in[7];
    const float* ln1b = (const float*)d_in[8];
    const float* ln2g = (const float*)d_in[9];
    const float* ln2b = (const float*)d_in[10];
    const float* Wff1 = (const float*)d_in[11];
    const float* bff1 = (const float*)d_in[12];
    const float* Wff2 = (const float*)d_in[13];
    const float* bff2 = (const float*)d_in[14];

    float* xc = (float*)d_out;

    // workspace layout (element counts are shorts unless noted)
    short* WqkvT = (short*)d_ws;              // [3072][1024]
    short* WoT   = WqkvT + 3145728;           // [1024][1024]
    short* Wff1T = WoT + 1048576;             // [4096][1024]
    short* Wff2T = Wff1T + 4194304;           // [1024][4096]
    short* WrT   = Wff2T + 4194304;           // [1024][1024]
    short* rbh   = WrT + 1048576;             // [2048][1024]
    short* xmemb = rbh + 2097152;             // [B*KL][1024]
    short* qbf   = xmemb + 4194304;           // [B*KL][1024]
    short* kbf   = qbf + 4194304;             // [B*KL][1024]
    short* vbf   = kbf + 4194304;             // [B*KL][1024]
    short* attnob= vbf + 4194304;             // [B*Q][1024]
    short* xcb   = attnob + 2097152;          // [B*Q][1024]
    short* ff1ob = xcb + 2097152;             // [B*Q][4096]
    float* addbuf= (float*)(ff1ob + 8388608); // [B*Q][1024] f32
    short* pbf   = ff1ob;                     // alias: p bf16 [2048][1024], pre-loop only

    // r = p @ W_r  (bf16 MFMA)
    transp_bf<<<dim3(32, 32), 256, 0, stream>>>(Wr, WrT, 1024, 1024);
    pos_emb_bf<<<(KL_ * D_) / 256, 256, 0, stream>>>(pbf);
    gemm_bf<0, 0, 1><<<dim3(8, 16), 256, 0, stream>>>(
        pbf, WrT, nullptr, nullptr, rbh, nullptr, nullptr, KL_, 1024, 1024);

    hipMemcpyAsync(xc, x, (size_t)B_ * Q_ * D_ * sizeof(float),
                   hipMemcpyDeviceToDevice, stream);

    for (int l = 0; l < L_; l++) {
        const float* mem_l = mem + (size_t)l * B_ * M_ * D_;

        transp_bf<<<dim3(96, 32), 256, 0, stream>>>(Wqkv + (size_t)l * 3145728, WqkvT, 1024, 3072);
        transp_bf<<<dim3(32, 32), 256, 0, stream>>>(Wo + (size_t)l * 1048576, WoT, 1024, 1024);
        transp_bf<<<dim3(128, 32), 256, 0, stream>>>(Wff1 + (size_t)l * 4194304, Wff1T, 1024, 4096);
        transp_bf<<<dim3(32, 128), 256, 0, stream>>>(Wff2 + (size_t)l * 4194304, Wff2T, 4096, 1024);

        concat_bf<<<(B_ * KL_ * D_) / 256, 256, 0, stream>>>(xmemb, mem_l, xc);

        gemm_bf<0, 0, 2><<<dim3(24, 32), 256, 0, stream>>>(
            xmemb, WqkvT, nullptr, nullptr, qbf, kbf, vbf, B_ * KL_, 3072, 1024);

        attn_mfma<<<B_ * H_ * (Q_ / 64), 256, 0, stream>>>(
            qbf, kbf, vbf, rbh, rwb, rrb, attnob);

        gemm_bf<0, 0, 0><<<dim3(8, 16), 256, 0, stream>>>(
            attnob, WoT, nullptr, addbuf, nullptr, nullptr, nullptr, B_ * Q_, 1024, 1024);

        ln_kernel<<<B_ * Q_, 256, 0, stream>>>(xc, xcb, addbuf, ln1g + l * D_, ln1b + l * D_);

        gemm_bf<1, 1, 1><<<dim3(32, 16), 256, 0, stream>>>(
            xcb, Wff1T, bff1 + (size_t)l * DI_, nullptr, ff1ob, nullptr, nullptr, B_ * Q_, 4096, 1024);

        gemm_bf<1, 0, 0><<<dim3(8, 16), 256, 0, stream>>>(
            ff1ob, Wff2T, bff2 + (size_t)l * D_, addbuf, nullptr, nullptr, nullptr, B_ * Q_, 1024, 4096);

        ln_kernel<<<B_ * Q_, 256, 0, stream>>>(xc, xcb, addbuf, ln2g + l * D_, ln2b + l * D_);
    }
}

// Round 4
// 1326.766 us; speedup vs baseline: 8.6405x; 1.0523x over previous
//
#include <hip/hip_runtime.h>
#include <math.h>

#define L_  4
#define B_  2
#define Q_  1024
#define M_  1024
#define D_  1024
#define H_  16
#define DH_ 64
#define DI_ 4096
#define KL_ (M_ + Q_)   // 2048

typedef __attribute__((ext_vector_type(8))) short short8v;  // 8 bf16 (4 VGPRs)
typedef __attribute__((ext_vector_type(4))) float f32x4;

__device__ __forceinline__ short f2bf(float f) {
    union { float f; unsigned u; } x; x.f = f;
    return (short)((x.u + 0x7FFFu + ((x.u >> 16) & 1)) >> 16);  // RNE
}
__device__ __forceinline__ unsigned pack2bf(float a, float b) {
    return (unsigned)(unsigned short)f2bf(a) | ((unsigned)(unsigned short)f2bf(b) << 16);
}
__device__ __forceinline__ float bf2f(unsigned short u) {
    union { unsigned u; float f; } x; x.u = (unsigned)u << 16; return x.f;
}
__device__ __forceinline__ void gload_lds16(const short* g, short* l) {
    __builtin_amdgcn_global_load_lds((const __attribute__((address_space(1))) unsigned int*)(const void*)g,
                                     (__attribute__((address_space(3))) unsigned int*)(void*)l, 16, 0, 0);
}
// XOR swizzle key (in shorts) for stride-64-short LDS tiles
__device__ __forceinline__ int swz(int row) {
    return ((row & 7) ^ ((row >> 3) & 7)) << 3;
}

// ---------------- positional embedding p[KL][D] (bf16) ----------------
__global__ __launch_bounds__(256) void pos_emb_bf(short* __restrict__ p) {
    int idx = blockIdx.x * 256 + threadIdx.x;
    int k = idx >> 10;
    int i = idx & (D_ - 1);
    float pos = (float)(KL_ - 1 - k);
    int j = (i < D_ / 2) ? i : (i - D_ / 2);
    float invf = powf(10000.0f, -((float)(2 * j) / (float)D_));
    float ang = pos * invf;
    p[idx] = f2bf((i < D_ / 2) ? sinf(ang) : cosf(ang));
}

// ---------------- concat memory[l] and x into xmemb [B][KL][D] bf16 ----------------
__global__ __launch_bounds__(256) void concat_bf(short* __restrict__ xmemb,
                                                 const float* __restrict__ mem_l,
                                                 const float* __restrict__ xc) {
    int idx = blockIdx.x * 256 + threadIdx.x;
    int d = idx & (D_ - 1);
    int k = (idx >> 10) & (KL_ - 1);
    int b = idx >> 21;
    float v = (k < M_) ? mem_l[((size_t)(b * M_ + k)) * D_ + d]
                       : xc[((size_t)(b * Q_ + (k - M_))) * D_ + d];
    xmemb[idx] = f2bf(v);
}

// ---------------- tiled transpose + f32->bf16: in[K][N] -> out[N][K] ----------------
__global__ __launch_bounds__(256) void transp_bf(const float* __restrict__ in,
                                                 short* __restrict__ out,
                                                 int K, int N) {
    __shared__ float t[32][33];
    int r = threadIdx.x >> 3, c4 = (threadIdx.x & 7) * 4;
    float4 v = *(const float4*)(in + (size_t)(blockIdx.y * 32 + r) * N + blockIdx.x * 32 + c4);
    t[r][c4 + 0] = v.x; t[r][c4 + 1] = v.y; t[r][c4 + 2] = v.z; t[r][c4 + 3] = v.w;
    __syncthreads();
    uint2 o;
    o.x = pack2bf(t[c4 + 0][r], t[c4 + 1][r]);
    o.y = pack2bf(t[c4 + 2][r], t[c4 + 3][r]);
    *(uint2*)(out + (size_t)(blockIdx.x * 32 + r) * K + blockIdx.y * 32 + c4) = o;
}

// ---------------- bf16 MFMA GEMM: C[M,N] = A[M,K] @ BT[N,K]^T ----------------
// 128xTN tile, BK=32, 4 waves. TN=128: wave=64x64 (4x4 frags); TN=64: wave=32x64 (2x4).
// OMODE: 0 = f32 out (Cf), 1 = bf16 out (C0), 2 = qkv 3-way bf16 split (C0/C1/C2)
template <int BIAS, int RELU, int OMODE, int TN>
__global__ __launch_bounds__(256, 2) void gemm_bf(const short* __restrict__ A,
                                                  const short* __restrict__ BT,
                                                  const float* __restrict__ bias,
                                                  float* __restrict__ Cf,
                                                  short* __restrict__ C0,
                                                  short* __restrict__ C1,
                                                  short* __restrict__ C2,
                                                  int M, int N, int K) {
    __shared__ short A_s[128 * 32];
    __shared__ short B_s[TN * 32];
    const int tid = threadIdx.x;
    const int lane = tid & 63, w = tid >> 6;
    const int l15 = lane & 15, l4 = lane >> 4;
    constexpr int MF = (TN == 128) ? 4 : 2;
    const int wr = (TN == 128) ? (w >> 1) : w;
    const int wc = (TN == 128) ? (w & 1) : 0;
    const int arow0 = 32 * ((TN == 128) ? 2 * wr : w);   // 64*wr or 32*w
    const int brow0 = (TN == 128) ? 64 * wc : 0;
    const int row0 = blockIdx.y * 128, col0 = blockIdx.x * TN;

    const int lrow = lane >> 2;
    const int lk = (lane & 3) * 8;
    const short* Ag = A + (size_t)(row0 + 32 * w) * K;
    const short* Bg = BT + (size_t)(col0 + ((TN == 128) ? 32 : 16) * w) * K;

    f32x4 acc[MF][4] = {};

    for (int k0 = 0; k0 < K; k0 += 32) {
        __syncthreads();
        gload_lds16(Ag + (size_t)lrow * K + k0 + lk,        &A_s[(32 * w) * 32]);
        gload_lds16(Ag + (size_t)(16 + lrow) * K + k0 + lk, &A_s[(32 * w + 16) * 32]);
        if (TN == 128) {
            gload_lds16(Bg + (size_t)lrow * K + k0 + lk,        &B_s[(32 * w) * 32]);
            gload_lds16(Bg + (size_t)(16 + lrow) * K + k0 + lk, &B_s[(32 * w + 16) * 32]);
        } else {
            gload_lds16(Bg + (size_t)lrow * K + k0 + lk,        &B_s[(16 * w) * 32]);
        }
        __syncthreads();
        short8v a[MF], bfr[4];
#pragma unroll
        for (int m = 0; m < MF; m++) a[m] = *(const short8v*)&A_s[(arow0 + 16 * m + l15) * 32 + 8 * l4];
#pragma unroll
        for (int n = 0; n < 4; n++) bfr[n] = *(const short8v*)&B_s[(brow0 + 16 * n + l15) * 32 + 8 * l4];
#pragma unroll
        for (int m = 0; m < MF; m++)
#pragma unroll
            for (int n = 0; n < 4; n++)
                acc[m][n] = __builtin_amdgcn_mfma_f32_16x16x32_bf16(a[m], bfr[n], acc[m][n], 0, 0, 0);
    }

#pragma unroll
    for (int n = 0; n < 4; n++) {
        int col = col0 + brow0 + 16 * n + l15;
        float bv = BIAS ? bias[col] : 0.0f;
#pragma unroll
        for (int m = 0; m < MF; m++) {
#pragma unroll
            for (int r = 0; r < 4; r++) {
                int row = row0 + arow0 + 16 * m + 4 * l4 + r;
                float v = acc[m][n][r] + bv;
                if (RELU) v = fmaxf(v, 0.0f);
                if (OMODE == 0) {
                    Cf[(size_t)row * N + col] = v;
                } else if (OMODE == 1) {
                    C0[(size_t)row * N + col] = f2bf(v);
                } else {
                    int part = col >> 10, cc = col & 1023;
                    short* dst = part == 0 ? C0 : (part == 1 ? C1 : C2);
                    dst[(size_t)row * 1024 + cc] = f2bf(v);
                }
            }
        }
    }
}

// ---------------- MFMA fused attention v2 ----------------
// block = (b, h, 64 q-rows); 4 waves, wave w owns rows [q0+16w, +16).
// Swizzled stride-64 LDS tiles; K/R staged via global_load_lds with pre-swizzled
// source; V transposed via conflict-free swizzled scalar writes; BD rel-shift
// extracted by register shuffles (no LDS round-trip); rolling 128-row R buffer.
__global__ __launch_bounds__(256, 3) void attn_mfma(const short* __restrict__ qbf,
                                                    const short* __restrict__ kbf,
                                                    const short* __restrict__ vbf,
                                                    const short* __restrict__ rbh,
                                                    const float* __restrict__ rwb,
                                                    const float* __restrict__ rrb,
                                                    short* __restrict__ attnob) {
    __shared__ short K_s[64 * 64];
    __shared__ short V_T[64 * 64];     // V_T[d][k], swizzled
    __shared__ short R_s[128 * 64];    // circular rows
    __shared__ short P_s[4][16 * 64];  // per-wave P, swizzled

    const int tid = threadIdx.x;
    const int lane = tid & 63, w = tid >> 6;
    const int l15 = lane & 15, l4 = lane >> 4;

    const int blk = blockIdx.x;
    const int qp = blk & 15;
    const int bh = blk >> 4;
    const int h = bh & 15, b = bh >> 4;
    const int qi = (qp & 1) ? (15 - (qp >> 1)) : (qp >> 1);   // work-pairing
    const int q0 = qi * 64;
    const int ntiles = qi + 17;
    const int jbase0 = (Q_ - 64) - q0;   // logical R row at phys 0

    // ---- Q frags: direct per-lane load + bias fuse ----
    size_t qrow = ((size_t)(b * KL_ + M_ + q0 + 16 * w + l15)) * 1024 + h * 64;
    union U8 { uint4 u; unsigned short us[8]; };
    U8 qa, qb2;
    qa.u  = *(const uint4*)(qbf + qrow + 8 * l4);
    qb2.u = *(const uint4*)(qbf + qrow + 32 + 8 * l4);
    short8v qwf0, qwf1, qrf0, qrf1;
#pragma unroll
    for (int i = 0; i < 8; i++) {
        float qv0 = bf2f(qa.us[i]), qv1 = bf2f(qb2.us[i]);
        int c0 = h * 64 + 8 * l4 + i, c1 = c0 + 32;
        qwf0[i] = f2bf(qv0 + rwb[c0]); qwf1[i] = f2bf(qv1 + rwb[c1]);
        qrf0[i] = f2bf(qv0 + rrb[c0]); qrf1[i] = f2bf(qv1 + rrb[c1]);
    }

    // ---- prologue staging: K/V rows 0..63, R phys rows 0..127 ----
    {
        const int lr8 = lane >> 3, oct = lane & 7;
        // K via gload_lds (pre-swizzled source), 2 calls/wave (8 rows each)
#pragma unroll
        for (int c = 0; c < 2; c++) {
            int R0 = 16 * w + 8 * c;
            int row = R0 + lr8;
            gload_lds16(kbf + ((size_t)(b * KL_) + row) * 1024 + h * 64 + ((oct * 8) ^ swz(row)),
                        &K_s[R0 * 64]);
        }
        // R via gload_lds, 4 calls/wave (32 rows each wave)
#pragma unroll
        for (int c = 0; c < 4; c++) {
            int R0 = 32 * w + 8 * c;
            int row = R0 + lr8;
            int jl = jbase0 + row;   // 0..1087, in range
            gload_lds16(rbh + (size_t)jl * 1024 + h * 64 + ((oct * 8) ^ swz(row)),
                        &R_s[R0 * 64]);
        }
        // V: reg-stage + swizzled scalar transpose writes
        const int d0 = (tid & 7) * 8;
#pragma unroll
        for (int it = 0; it < 2; it++) {
            int rr = (tid + it * 256) >> 3;   // 0..63
            U8 cv; cv.u = *(const uint4*)(vbf + ((size_t)(b * KL_) + rr) * 1024 + h * 64 + d0);
#pragma unroll
            for (int i = 0; i < 8; i++)
                V_T[(d0 + i) * 64 + (rr ^ swz(d0 + i))] = (short)cv.us[i];
        }
    }
    __syncthreads();

    f32x4 o[4];
    float m_r[4], l_r[4];
#pragma unroll
    for (int j = 0; j < 4; j++) o[j] = (f32x4){0.f, 0.f, 0.f, 0.f};
#pragma unroll
    for (int r = 0; r < 4; r++) { m_r[r] = -1e30f; l_r[r] = 0.0f; }

    int sl[4];
#pragma unroll
    for (int r = 0; r < 4; r++)
        sl[r] = (lane & 48) | ((l15 + 15 - (4 * l4 + r)) & 15);

    short* P_w = &P_s[w][0];

    for (int t = 0; t < ntiles; t++) {
        const bool pf = (t + 1 < ntiles);
        const int d0 = (tid & 7) * 8;
        // early-issue V loads for t+1 (latency hides under compute)
        uint4 pv2[2];
        if (pf) {
#pragma unroll
            for (int it = 0; it < 2; it++) {
                int rr = (tid + it * 256) >> 3;
                pv2[it] = *(const uint4*)(vbf + ((size_t)(b * KL_) + 64 * (t + 1) + rr) * 1024 + h * 64 + d0);
            }
        }

        // ---- AC = Qw · K^T ----
        f32x4 ac[4];
        __builtin_amdgcn_s_setprio(1);
#pragma unroll
        for (int j = 0; j < 4; j++) {
            int kk = 16 * j + l15, sz = swz(kk);
            short8v b0 = *(const short8v*)&K_s[kk * 64 + ((8 * l4) ^ sz)];
            short8v b1 = *(const short8v*)&K_s[kk * 64 + ((32 + 8 * l4) ^ sz)];
            f32x4 z = {0.f, 0.f, 0.f, 0.f};
            z = __builtin_amdgcn_mfma_f32_16x16x32_bf16(qwf0, b0, z, 0, 0, 0);
            z = __builtin_amdgcn_mfma_f32_16x16x32_bf16(qwf1, b1, z, 0, 0, 0);
            ac[j] = z;
        }
        // ---- BDraw strips (kept in registers) ----
        f32x4 zf[5];
#pragma unroll
        for (int jb = 0; jb < 5; jb++) {
            int rp = (64 * t + 16 * (3 - w) + 16 * jb + l15) & 127;
            int sz = swz(rp);
            short8v b0 = *(const short8v*)&R_s[rp * 64 + ((8 * l4) ^ sz)];
            short8v b1 = *(const short8v*)&R_s[rp * 64 + ((32 + 8 * l4) ^ sz)];
            f32x4 z = {0.f, 0.f, 0.f, 0.f};
            z = __builtin_amdgcn_mfma_f32_16x16x32_bf16(qrf0, b0, z, 0, 0, 0);
            z = __builtin_amdgcn_mfma_f32_16x16x32_bf16(qrf1, b1, z, 0, 0, 0);
            zf[jb] = z;
        }
        __builtin_amdgcn_s_setprio(0);

        // ---- scores: shift-extract BD via shuffles, mask, online softmax ----
        float sv[4][4], mloc[4];
#pragma unroll
        for (int r = 0; r < 4; r++) mloc[r] = -1e30f;
#pragma unroll
        for (int j = 0; j < 4; j++) {
#pragma unroll
            for (int r = 0; r < 4; r++) {
                int row = 4 * l4 + r;
                float blo = __shfl(zf[j][r], sl[r]);
                float bhi = __shfl(zf[j + 1][r], sl[r]);
                float bd = (l15 > row) ? bhi : blo;
                float s = (ac[j][r] + bd) * 0.125f;
                if (64 * t + 16 * j + l15 > q0 + 16 * w + row + M_) s = -1e30f;
                sv[j][r] = s;
                mloc[r] = fmaxf(mloc[r], s);
            }
        }
#pragma unroll
        for (int r = 0; r < 4; r++) {
            float v = mloc[r];
            v = fmaxf(v, __shfl_xor(v, 1));
            v = fmaxf(v, __shfl_xor(v, 2));
            v = fmaxf(v, __shfl_xor(v, 4));
            v = fmaxf(v, __shfl_xor(v, 8));
            float mnew = fmaxf(m_r[r], v);
            float c = __expf(m_r[r] - mnew);
            m_r[r] = mnew;
            l_r[r] *= c;
#pragma unroll
            for (int jd = 0; jd < 4; jd++) o[jd][r] *= c;
            mloc[r] = 0.0f;
        }
#pragma unroll
        for (int j = 0; j < 4; j++) {
#pragma unroll
            for (int r = 0; r < 4; r++) {
                float pp = __expf(sv[j][r] - m_r[r]);
                sv[j][r] = pp;
                mloc[r] += pp;
            }
        }
#pragma unroll
        for (int r = 0; r < 4; r++) {
            float v = mloc[r];
            v += __shfl_xor(v, 1);
            v += __shfl_xor(v, 2);
            v += __shfl_xor(v, 4);
            v += __shfl_xor(v, 8);
            l_r[r] += v;
        }

        // ---- P -> per-wave swizzled LDS -> A-frags; PV ----
#pragma unroll
        for (int j = 0; j < 4; j++) {
#pragma unroll
            for (int r = 0; r < 4; r++) {
                int row = 4 * l4 + r;
                P_w[row * 64 + ((16 * j + l15) ^ swz(row))] = f2bf(sv[j][r]);
            }
        }
        int szp = swz(l15);
        short8v pa0 = *(const short8v*)&P_w[l15 * 64 + ((8 * l4) ^ szp)];
        short8v pa1 = *(const short8v*)&P_w[l15 * 64 + ((32 + 8 * l4) ^ szp)];
        __builtin_amdgcn_s_setprio(1);
#pragma unroll
        for (int jd = 0; jd < 4; jd++) {
            int dd = 16 * jd + l15, sz = swz(dd);
            short8v v0 = *(const short8v*)&V_T[dd * 64 + ((8 * l4) ^ sz)];
            short8v v1 = *(const short8v*)&V_T[dd * 64 + ((32 + 8 * l4) ^ sz)];
            o[jd] = __builtin_amdgcn_mfma_f32_16x16x32_bf16(pa0, v0, o[jd], 0, 0, 0);
            o[jd] = __builtin_amdgcn_mfma_f32_16x16x32_bf16(pa1, v1, o[jd], 0, 0, 0);
        }
        __builtin_amdgcn_s_setprio(0);

        __syncthreads();
        if (pf) {
            const int lr8 = lane >> 3, oct = lane & 7;
            // K for t+1 via gload_lds
#pragma unroll
            for (int c = 0; c < 2; c++) {
                int R0 = 16 * w + 8 * c;
                int row = R0 + lr8;
                gload_lds16(kbf + ((size_t)(b * KL_) + 64 * (t + 1) + row) * 1024 + h * 64 + ((oct * 8) ^ swz(row)),
                            &K_s[R0 * 64]);
            }
            // R: 64 new rows into circular buffer
#pragma unroll
            for (int c = 0; c < 2; c++) {
                int R0 = 16 * w + 8 * c;
                int pbase = (64 * t + R0) & 127;
                int prow = pbase + lr8;
                int jl = jbase0 + 64 * t + 128 + R0 + lr8;
                if (jl > KL_ - 1) jl = KL_ - 1;
                gload_lds16(rbh + (size_t)jl * 1024 + h * 64 + ((oct * 8) ^ swz(prow)),
                            &R_s[pbase * 64]);
            }
            // V transpose writes (regs loaded early)
#pragma unroll
            for (int it = 0; it < 2; it++) {
                int rr = (tid + it * 256) >> 3;
                U8 cv; cv.u = pv2[it];
#pragma unroll
                for (int i = 0; i < 8; i++)
                    V_T[(d0 + i) * 64 + (rr ^ swz(d0 + i))] = (short)cv.us[i];
            }
        }
        __syncthreads();
    }

    // ---- normalize + store ----
#pragma unroll
    for (int jd = 0; jd < 4; jd++) {
#pragma unroll
        for (int r = 0; r < 4; r++) {
            int qg = q0 + 16 * w + 4 * l4 + r;
            int dv = 16 * jd + l15;
            attnob[((size_t)(b * Q_ + qg)) * (H_ * DH_) + h * 64 + dv] = f2bf(o[jd][r] / l_r[r]);
        }
    }
}

// ---------------- layernorm: x = LN(x + add) * g + b ; dual f32+bf16 out ----------------
__global__ __launch_bounds__(256) void ln_kernel(float* __restrict__ x,
                                                 short* __restrict__ xb,
                                                 const float* __restrict__ add,
                                                 const float* __restrict__ g,
                                                 const float* __restrict__ bb) {
    __shared__ float red[256];
    int row = blockIdx.x;
    int tid = threadIdx.x;
    float v[4];
    float s = 0.0f;
#pragma unroll
    for (int i = 0; i < 4; i++) {
        int c = tid + i * 256;
        v[i] = x[(size_t)row * D_ + c] + add[(size_t)row * D_ + c];
        s += v[i];
    }
    red[tid] = s;
    __syncthreads();
    for (int o = 128; o; o >>= 1) {
        if (tid < o) red[tid] += red[tid + o];
        __syncthreads();
    }
    float mu = red[0] / D_;
    __syncthreads();
    float sq = 0.0f;
#pragma unroll
    for (int i = 0; i < 4; i++) {
        float dd = v[i] - mu;
        sq += dd * dd;
    }
    red[tid] = sq;
    __syncthreads();
    for (int o = 128; o; o >>= 1) {
        if (tid < o) red[tid] += red[tid + o];
        __syncthreads();
    }
    float var = red[0] / D_;
    float rs = rsqrtf(var + 1e-5f);
#pragma unroll
    for (int i = 0; i < 4; i++) {
        int c = tid + i * 256;
        float ov = (v[i] - mu) * rs * g[c] + bb[c];
        x[(size_t)row * D_ + c] = ov;
        xb[(size_t)row * D_ + c] = f2bf(ov);
    }
}

extern "C" void kernel_launch(void* const* d_in, const int* in_sizes, int n_in,
                              void* d_out, int out_size, void* d_ws, size_t ws_size,
                              hipStream_t stream) {
    const float* x    = (const float*)d_in[0];
    const float* mem  = (const float*)d_in[1];
    const float* Wqkv = (const float*)d_in[2];
    const float* Wr   = (const float*)d_in[3];
    const float* Wo   = (const float*)d_in[4];
    const float* rwb  = (const float*)d_in[5];
    const float* rrb  = (const float*)d_in[6];
    const float* ln1g = (const float*)d_in[7];
    const float* ln1b = (const float*)d_in[8];
    const float* ln2g = (const float*)d_in[9];
    const float* ln2b = (const float*)d_in[10];
    const float* Wff1 = (const float*)d_in[11];
    const float* bff1 = (const float*)d_in[12];
    const float* Wff2 = (const float*)d_in[13];
    const float* bff2 = (const float*)d_in[14];

    float* xc = (float*)d_out;

    // workspace layout (shorts unless noted)
    short* WqkvT = (short*)d_ws;              // [3072][1024]
    short* WoT   = WqkvT + 3145728;           // [1024][1024]
    short* Wff1T = WoT + 1048576;             // [4096][1024]
    short* Wff2T = Wff1T + 4194304;           // [1024][4096]
    short* WrT   = Wff2T + 4194304;           // [1024][1024]
    short* rbh   = WrT + 1048576;             // [2048][1024]
    short* xmemb = rbh + 2097152;             // [B*KL][1024]
    short* qbf   = xmemb + 4194304;           // [B*KL][1024]
    short* kbf   = qbf + 4194304;             // [B*KL][1024]
    short* vbf   = kbf + 4194304;             // [B*KL][1024]
    short* attnob= vbf + 4194304;             // [B*Q][1024]
    short* xcb   = attnob + 2097152;          // [B*Q][1024]
    short* ff1ob = xcb + 2097152;             // [B*Q][4096]
    float* addbuf= (float*)(ff1ob + 8388608); // [B*Q][1024] f32
    short* pbf   = ff1ob;                     // alias: p bf16 [2048][1024], pre-loop only

    // r = p @ W_r  (bf16 MFMA)
    transp_bf<<<dim3(32, 32), 256, 0, stream>>>(Wr, WrT, 1024, 1024);
    pos_emb_bf<<<(KL_ * D_) / 256, 256, 0, stream>>>(pbf);
    gemm_bf<0, 0, 1, 64><<<dim3(16, 16), 256, 0, stream>>>(
        pbf, WrT, nullptr, nullptr, rbh, nullptr, nullptr, KL_, 1024, 1024);

    hipMemcpyAsync(xc, x, (size_t)B_ * Q_ * D_ * sizeof(float),
                   hipMemcpyDeviceToDevice, stream);

    for (int l = 0; l < L_; l++) {
        const float* mem_l = mem + (size_t)l * B_ * M_ * D_;

        transp_bf<<<dim3(96, 32), 256, 0, stream>>>(Wqkv + (size_t)l * 3145728, WqkvT, 1024, 3072);
        transp_bf<<<dim3(32, 32), 256, 0, stream>>>(Wo + (size_t)l * 1048576, WoT, 1024, 1024);
        transp_bf<<<dim3(128, 32), 256, 0, stream>>>(Wff1 + (size_t)l * 4194304, Wff1T, 1024, 4096);
        transp_bf<<<dim3(32, 128), 256, 0, stream>>>(Wff2 + (size_t)l * 4194304, Wff2T, 4096, 1024);

        concat_bf<<<(B_ * KL_ * D_) / 256, 256, 0, stream>>>(xmemb, mem_l, xc);

        gemm_bf<0, 0, 2, 128><<<dim3(24, 32), 256, 0, stream>>>(
            xmemb, WqkvT, nullptr, nullptr, qbf, kbf, vbf, B_ * KL_, 3072, 1024);

        attn_mfma<<<B_ * H_ * (Q_ / 64), 256, 0, stream>>>(
            qbf, kbf, vbf, rbh, rwb, rrb, attnob);

        gemm_bf<0, 0, 0, 64><<<dim3(16, 16), 256, 0, stream>>>(
            attnob, WoT, nullptr, addbuf, nullptr, nullptr, nullptr, B_ * Q_, 1024, 1024);

        ln_kernel<<<B_ * Q_, 256, 0, stream>>>(xc, xcb, addbuf, ln1g + l * D_, ln1b + l * D_);

        gemm_bf<1, 1, 1, 128><<<dim3(32, 16), 256, 0, stream>>>(
            xcb, Wff1T, bff1 + (size_t)l * DI_, nullptr, ff1ob, nullptr, nullptr, B_ * Q_, 4096, 1024);

        gemm_bf<1, 0, 0, 64><<<dim3(16, 16), 256, 0, stream>>>(
            ff1ob, Wff2T, bff2 + (size_t)l * D_, addbuf, nullptr, nullptr, nullptr, B_ * Q_, 1024, 4096);

        ln_kernel<<<B_ * Q_, 256, 0, stream>>>(xc, xcb, addbuf, ln2g + l * D_, ln2b + l * D_);
    }
}